// Round 1
// 218.645 us; speedup vs baseline: 1.0129x; 1.0129x over previous
//
#include <hip/hip_runtime.h>

// FilterInterpolation, round 8.
// out[b,ch,y,x] = mask * sum_{r,c in 5x5} W5[r][c] * img[b,ch, clip(iyT+r), clip(ixL+c)]
//
// R7 analysis: total dur_us = ~158us harness re-poison fills (2x 79us
// fillBufferAligned, 510MB each -- not controllable) + ~63us kernel.
// Kernel model: ~38us HBM + ~21us VALU + ~16us LDS-issue, poorly overlapped.
// float3 taps cost 2 ds_read (can't prove 16B align) + 3 scalar FMAs each.
//
// R8: float4-per-tap LDS tile (aligned v4f -> one ds_read_b128 per tap for all
// 3 channels, accumulate via v_pk_fma_f32: 25 LDS instr + ~50 VALU per pixel,
// was ~50 + 75). R6's float4 failure was UNALIGNED float* reads (b32 at
// word-stride 4 -> 8-way conflicts); aligned v4f avoids it. Lane mapping is
// half-split (x0+xp, x0+32+xp) instead of interleaved pairs so lane ixL
// stride ~1 spreads the b128 quad-bank groups (base%8 covers all 8 groups,
// not just even ones). Geometry/occupancy unchanged: 24.6KB LDS, 256 thr.

#define BB 4
#define HH 544
#define WW 960
#define HW (HH * WW)

#define BX 64          // block pixels in x
#define BY 8           // block pixels in y
#define MARG 6         // tile margin
#define TW (BX + 2 * MARG)   // 76 tile cols
#define TH (BY + 2 * MARG)   // 20 tile rows
#define RS4 (TW + 1)         // 77 float4s per LDS row (odd -> rows shift bank-group by 5)

typedef float v4f __attribute__((ext_vector_type(4)));

__global__ __launch_bounds__(256) void filt_interp_kernel(
    const float* __restrict__ img,   // (B,3,H,W)
    const float* __restrict__ flow,  // (B,2,H,W)
    const float* __restrict__ filt,  // (B,16,H,W)
    float* __restrict__ out)         // (B,3,H,W)
{
    __shared__ v4f tile[TH * RS4];   // 20*77*16 = 24,640 B -> 6 blocks/CU LDS-cap

    const int tid = threadIdx.x;
    const int x0 = blockIdx.x * BX;
    const int y0 = blockIdx.y * BY;
    const int b  = blockIdx.z;
    const int tx0 = x0 - MARG;
    const int ty0 = y0 - MARG;

    // ---- stage clipped, channel-packed (float4: c0,c1,c2,0) tile ----
    const float* ibase = img + (size_t)b * 3 * HW;
    for (int li = tid; li < TH * TW; li += 256) {
        int vr = li / TW;
        int vc = li - vr * TW;
        int gy = min(max(ty0 + vr, 0), HH - 1);
        int gx = min(max(tx0 + vc, 0), WW - 1);
        const float* ip = ibase + gy * WW + gx;
        v4f t;
        t.x = ip[0];
        t.y = ip[HW];
        t.z = ip[2 * HW];
        t.w = 0.0f;
        tile[vr * RS4 + vc] = t;     // ds_write_b128, lane-consecutive -> conflict-free
    }
    __syncthreads();

    // ---- per-thread: two pixels, half-split (xb and xb+32) ----
    const int xp = tid & 31;
    const int yr = tid >> 5;          // 0..7
    const int xb = x0 + xp;           // k=0 pixel; k=1 pixel is xb+32
    const int y = y0 + yr;
    const int pix = y * WW + xb;

    // Batch all stream loads up-front (independent -> deep MLP).
    const float* flp = flow + (size_t)b * 2 * HW + pix;
    float fxk[2], fyk[2];
    fxk[0] = __builtin_nontemporal_load(flp);
    fxk[1] = __builtin_nontemporal_load(flp + 32);
    fyk[0] = __builtin_nontemporal_load(flp + HW);
    fyk[1] = __builtin_nontemporal_load(flp + HW + 32);

    const float* fp = filt + (size_t)b * 16 * HW + pix;
    float w3k[2][16];
#pragma unroll
    for (int t = 0; t < 16; t++) {
        w3k[0][t] = __builtin_nontemporal_load(fp + (size_t)t * HW);
        w3k[1][t] = __builtin_nontemporal_load(fp + (size_t)t * HW + 32);
    }

    float res[2][3];

#pragma unroll
    for (int k = 0; k < 2; k++) {
        const int xk = xb + 32 * k;
        float fx = fxk[k];
        float fy = fyk[k];
        float x2 = (float)xk + fx;
        float y2 = (float)y + fy;
        bool m = (x2 >= 0.0f) && (y2 >= 0.0f) &&
                 (x2 <= (float)(WW - 1)) && (y2 <= (float)(HH - 1)) &&
                 (fabsf(fx) < (float)WW * 0.5f) && (fabsf(fy) < (float)HH * 0.5f);
        float x2c = fminf(fmaxf(x2, 0.0f), (float)(WW - 1));
        float y2c = fminf(fmaxf(y2, 0.0f), (float)(HH - 1));
        int ix = (int)floorf(x2c);
        int iy = (int)floorf(y2c);
        float alpha = x2c - (float)ix;
        float beta  = y2c - (float)iy;
        int ixL = ix - 1;   // ix + 1 - fs/2
        int iyT = iy - 1;
        float mf = m ? 1.0f : 0.0f;
        float wa = (1.0f - alpha) * (1.0f - beta) * mf;
        float wb = alpha * (1.0f - beta) * mf;
        float wc = (1.0f - alpha) * beta * mf;
        float wd = alpha * beta * mf;

        // Build 5x5 combined weights (mask pre-folded via wa..wd).
        float W5[5][5];
#pragma unroll
        for (int r = 0; r < 5; r++)
#pragma unroll
            for (int c = 0; c < 5; c++) W5[r][c] = 0.0f;

#pragma unroll
        for (int j = 0; j < 4; j++) {
#pragma unroll
            for (int i = 0; i < 4; i++) {
                float w3 = w3k[k][j * 4 + i];
                W5[j][i]         += wa * w3;
                W5[j][i + 1]     += wb * w3;
                W5[j + 1][i]     += wc * w3;
                W5[j + 1][i + 1] += wd * w3;
            }
        }

        bool ok = (iyT >= ty0) && (iyT + 4 <= ty0 + TH - 1) &&
                  (ixL >= tx0) && (ixL + 4 <= tx0 + TW - 1);

        if (ok) {
            int base = (iyT - ty0) * RS4 + (ixL - tx0);
            v4f acc = {0.0f, 0.0f, 0.0f, 0.0f};
#pragma unroll
            for (int r = 0; r < 5; r++) {
#pragma unroll
                for (int c = 0; c < 5; c++) {
                    // one ds_read_b128 + 2x v_pk_fma_f32 per tap
                    acc += W5[r][c] * tile[base + r * RS4 + c];
                }
            }
            res[k][0] = acc.x;
            res[k][1] = acc.y;
            res[k][2] = acc.z;
        } else {
            // Rare fallback (|flow| tail): direct clipped global gathers.
            float ax = 0.0f, ay = 0.0f, az = 0.0f;
            int cx[5], ry[5];
#pragma unroll
            for (int q = 0; q < 5; q++) {
                cx[q] = min(max(ixL + q, 0), WW - 1);
                ry[q] = min(max(iyT + q, 0), HH - 1);
            }
#pragma unroll
            for (int r = 0; r < 5; r++) {
                const float* rowp = ibase + ry[r] * WW;
#pragma unroll
                for (int c = 0; c < 5; c++) {
                    float w = W5[r][c];
                    const float* p = rowp + cx[c];
                    ax = fmaf(w, p[0], ax);
                    ay = fmaf(w, p[HW], ay);
                    az = fmaf(w, p[2 * HW], az);
                }
            }
            res[k][0] = ax;
            res[k][1] = ay;
            res[k][2] = az;
        }
    }

    float* ob = out + (size_t)b * 3 * HW + pix;
#pragma unroll
    for (int ch = 0; ch < 3; ch++) {
        __builtin_nontemporal_store(res[0][ch], ob + (size_t)ch * HW);
        __builtin_nontemporal_store(res[1][ch], ob + (size_t)ch * HW + 32);
    }
}

extern "C" void kernel_launch(void* const* d_in, const int* in_sizes, int n_in,
                              void* d_out, int out_size, void* d_ws, size_t ws_size,
                              hipStream_t stream) {
    const float* img  = (const float*)d_in[0];
    const float* flow = (const float*)d_in[1];
    const float* filt = (const float*)d_in[2];
    float* out = (float*)d_out;

    dim3 grid(WW / BX, HH / BY, BB);   // 15 x 68 x 4 = 4080 blocks
    filt_interp_kernel<<<grid, 256, 0, stream>>>(img, flow, filt, out);
}

// Round 2
// 217.799 us; speedup vs baseline: 1.0169x; 1.0039x over previous
//
#include <hip/hip_runtime.h>

// FilterInterpolation, round 9.
// out[b,ch,y,x] = mask * sum_{r,c in 5x5} W5[r][c] * img[b,ch, clip(iyT+r), clip(ixL+c)]
//
// Budget: dur_us = ~158us harness re-poison fills (fixed) + ~60us kernel.
// Kernel pipes: HBM ~32us (200MB compulsory; img margins L3-absorbed),
// VALU ~26us, LDS ~15us. R9 attacks VALU + L2 locality:
//  1) SADDR addressing: flow/filt/out loads keep a UNIFORM base pointer and
//     per-lane pix voffset -> t*HW folds into s_add (SALU), kills ~64
//     v_add64 pairs/thread that R8 paid by baking pix into the base pointer.
//  2) Mul-first W5 build: first contribution per cell is an assignment (mul),
//     not zero-init + fma -> kills 50 v_mov/thread.
//  3) XCD-chunked swizzle (4080 = 8*510, bijective): each XCD owns a
//     contiguous 34-block-row band of one batch image (3.1MB < 4MB L2), so
//     tile-margin re-reads hit local L2 (default dispatch puts x- and
//     y-neighbors on different XCDs: +1 and +15 mod 8 != 0).
// Geometry/mapping unchanged from R8: v4f tile, half-split lanes, 24.6KB LDS.

#define BB 4
#define HH 544
#define WW 960
#define HW (HH * WW)

#define BX 64          // block pixels in x
#define BY 8           // block pixels in y
#define MARG 6         // tile margin
#define TW (BX + 2 * MARG)   // 76 tile cols
#define TH (BY + 2 * MARG)   // 20 tile rows
#define RS4 (TW + 1)         // 77 float4s per LDS row (odd -> rows shift bank-group by 5)

#define GXB (WW / BX)        // 15
#define GYB (HH / BY)        // 68
#define NWG (GXB * GYB * BB) // 4080
#define CHUNK (NWG / 8)      // 510 blocks per XCD

typedef float v4f __attribute__((ext_vector_type(4)));

__global__ __launch_bounds__(256) void filt_interp_kernel(
    const float* __restrict__ img,   // (B,3,H,W)
    const float* __restrict__ flow,  // (B,2,H,W)
    const float* __restrict__ filt,  // (B,16,H,W)
    float* __restrict__ out)         // (B,3,H,W)
{
    __shared__ v4f tile[TH * RS4];   // 20*77*16 = 24,640 B -> 6 blocks/CU LDS-cap

    // ---- XCD-chunked bijective swizzle (scalar math on uniform blockIdx) ----
    const int wg  = blockIdx.x;
    const int swz = (wg & 7) * CHUNK + (wg >> 3);
    const int b   = swz / (GXB * GYB);
    const int rem = swz - b * (GXB * GYB);
    const int by  = rem / GXB;
    const int bx  = rem - by * GXB;

    const int tid = threadIdx.x;
    const int x0 = bx * BX;
    const int y0 = by * BY;
    const int tx0 = x0 - MARG;
    const int ty0 = y0 - MARG;

    // ---- stage clipped, channel-packed (float4: c0,c1,c2,0) tile ----
    // Uniform channel bases -> saddr-form loads with 32-bit voffset.
    const float* ib0 = img + (size_t)b * 3 * HW;
    const float* ib1 = ib0 + HW;
    const float* ib2 = ib0 + 2 * HW;
    for (int li = tid; li < TH * TW; li += 256) {
        int vr = li / TW;
        int vc = li - vr * TW;
        int gy = min(max(ty0 + vr, 0), HH - 1);
        int gx = min(max(tx0 + vc, 0), WW - 1);
        int gi = gy * WW + gx;
        v4f t;
        t.x = ib0[gi];
        t.y = ib1[gi];
        t.z = ib2[gi];
        t.w = 0.0f;
        tile[vr * RS4 + vc] = t;     // ds_write_b128, lane-consecutive -> conflict-free
    }
    __syncthreads();

    // ---- per-thread: two pixels, half-split (xb and xb+32) ----
    const int xp = tid & 31;
    const int yr = tid >> 5;          // 0..7
    const int xb = x0 + xp;           // k=0 pixel; k=1 pixel is xb+32
    const int y = y0 + yr;
    const int pix = y * WW + xb;

    // Batch all stream loads up-front (independent -> deep MLP).
    // Uniform bases; per-lane offset is pix only -> saddr codegen, no v_add64.
    const float* fb = flow + (size_t)b * 2 * HW;
    float fxk[2], fyk[2];
    fxk[0] = __builtin_nontemporal_load(fb + pix);
    fxk[1] = __builtin_nontemporal_load(fb + pix + 32);
    fyk[0] = __builtin_nontemporal_load(fb + HW + pix);
    fyk[1] = __builtin_nontemporal_load(fb + HW + pix + 32);

    const float* ftb = filt + (size_t)b * 16 * HW;
    float w3k[2][16];
#pragma unroll
    for (int t = 0; t < 16; t++) {
        w3k[0][t] = __builtin_nontemporal_load(ftb + (size_t)t * HW + pix);
        w3k[1][t] = __builtin_nontemporal_load(ftb + (size_t)t * HW + pix + 32);
    }

    float res[2][3];

#pragma unroll
    for (int k = 0; k < 2; k++) {
        const int xk = xb + 32 * k;
        float fx = fxk[k];
        float fy = fyk[k];
        float x2 = (float)xk + fx;
        float y2 = (float)y + fy;
        bool m = (x2 >= 0.0f) && (y2 >= 0.0f) &&
                 (x2 <= (float)(WW - 1)) && (y2 <= (float)(HH - 1)) &&
                 (fabsf(fx) < (float)WW * 0.5f) && (fabsf(fy) < (float)HH * 0.5f);
        float x2c = fminf(fmaxf(x2, 0.0f), (float)(WW - 1));
        float y2c = fminf(fmaxf(y2, 0.0f), (float)(HH - 1));
        int ix = (int)floorf(x2c);
        int iy = (int)floorf(y2c);
        float alpha = x2c - (float)ix;
        float beta  = y2c - (float)iy;
        int ixL = ix - 1;   // ix + 1 - fs/2
        int iyT = iy - 1;
        float mf = m ? 1.0f : 0.0f;
        float wa = (1.0f - alpha) * (1.0f - beta) * mf;
        float wb = alpha * (1.0f - beta) * mf;
        float wc = (1.0f - alpha) * beta * mf;
        float wd = alpha * beta * mf;

        // Build 5x5 combined weights, mul-first per cell (no zero-init movs).
        // First contributor per cell in (j asc, i asc) tap order:
        //   cell(j,i)   wa-term first iff j==0 && i==0
        //   cell(j,i+1) wb-term first iff j==0
        //   cell(j+1,i) wc-term first iff i==0
        //   cell(j+1,i+1) wd-term always first
        float W5[5][5];
#pragma unroll
        for (int j = 0; j < 4; j++) {
#pragma unroll
            for (int i = 0; i < 4; i++) {
                float w3 = w3k[k][j * 4 + i];
                if (j == 0 && i == 0) W5[j][i] = wa * w3;
                else                  W5[j][i] = fmaf(wa, w3, W5[j][i]);
                if (j == 0)           W5[j][i + 1] = wb * w3;
                else                  W5[j][i + 1] = fmaf(wb, w3, W5[j][i + 1]);
                if (i == 0)           W5[j + 1][i] = wc * w3;
                else                  W5[j + 1][i] = fmaf(wc, w3, W5[j + 1][i]);
                W5[j + 1][i + 1] = wd * w3;
            }
        }

        bool ok = (iyT >= ty0) && (iyT + 4 <= ty0 + TH - 1) &&
                  (ixL >= tx0) && (ixL + 4 <= tx0 + TW - 1);

        if (ok) {
            int base = (iyT - ty0) * RS4 + (ixL - tx0);
            v4f acc = {0.0f, 0.0f, 0.0f, 0.0f};
#pragma unroll
            for (int r = 0; r < 5; r++) {
#pragma unroll
                for (int c = 0; c < 5; c++) {
                    // one ds_read_b128 (offset-imm) + 2x v_pk_fma_f32 per tap
                    acc += W5[r][c] * tile[base + r * RS4 + c];
                }
            }
            res[k][0] = acc.x;
            res[k][1] = acc.y;
            res[k][2] = acc.z;
        } else {
            // Rare fallback (|flow| tail): direct clipped global gathers.
            float ax = 0.0f, ay = 0.0f, az = 0.0f;
            int cx[5], ry[5];
#pragma unroll
            for (int q = 0; q < 5; q++) {
                cx[q] = min(max(ixL + q, 0), WW - 1);
                ry[q] = min(max(iyT + q, 0), HH - 1);
            }
#pragma unroll
            for (int r = 0; r < 5; r++) {
                int rowb = ry[r] * WW;
#pragma unroll
                for (int c = 0; c < 5; c++) {
                    float w = W5[r][c];
                    int gi = rowb + cx[c];
                    ax = fmaf(w, ib0[gi], ax);
                    ay = fmaf(w, ib1[gi], ay);
                    az = fmaf(w, ib2[gi], az);
                }
            }
            res[k][0] = ax;
            res[k][1] = ay;
            res[k][2] = az;
        }
    }

    // Uniform channel bases for stores -> saddr form.
    float* ob = out + (size_t)b * 3 * HW;
#pragma unroll
    for (int ch = 0; ch < 3; ch++) {
        __builtin_nontemporal_store(res[0][ch], ob + (size_t)ch * HW + pix);
        __builtin_nontemporal_store(res[1][ch], ob + (size_t)ch * HW + pix + 32);
    }
}

extern "C" void kernel_launch(void* const* d_in, const int* in_sizes, int n_in,
                              void* d_out, int out_size, void* d_ws, size_t ws_size,
                              hipStream_t stream) {
    const float* img  = (const float*)d_in[0];
    const float* flow = (const float*)d_in[1];
    const float* filt = (const float*)d_in[2];
    float* out = (float*)d_out;

    filt_interp_kernel<<<dim3(NWG), 256, 0, stream>>>(img, flow, filt, out);
}